// Round 1
// baseline (437.587 us; speedup 1.0000x reference)
//
#include <hip/hip_runtime.h>
#include <cstdint>
#include <cstddef>

constexpr int kN = 10000;   // nodes
constexpr int kE = 320000;  // edges
constexpr int kM = 4;       // modalities
constexpr int kD = 256;     // feature dim
constexpr int kP = 256;     // pro dim
constexpr float kSlope = 0.2f;

constexpr int BM = 64, BN = 64, BK = 16;

// ---------------- graph build ----------------

__global__ void deg_count_kernel(const int* __restrict__ ei, int* __restrict__ deg) {
  int e = blockIdx.x * 256 + threadIdx.x;
  if (e < kE) atomicAdd(&deg[ei[kE + e]], 1);   // dst row of edge_index
}

__global__ void scan_kernel(const int* __restrict__ deg, int* __restrict__ offs) {
  __shared__ int buf[1024];
  __shared__ int carry_s;
  if (threadIdx.x == 0) { carry_s = 0; offs[0] = 0; }
  __syncthreads();
  for (int base = 0; base < kN; base += 1024) {
    int i = base + threadIdx.x;
    int v = (i < kN) ? deg[i] : 0;
    buf[threadIdx.x] = v;
    __syncthreads();
    for (int o = 1; o < 1024; o <<= 1) {
      int t = (threadIdx.x >= o) ? buf[threadIdx.x - o] : 0;
      __syncthreads();
      buf[threadIdx.x] += t;
      __syncthreads();
    }
    int inc = buf[threadIdx.x] + carry_s;
    if (i < kN) offs[i + 1] = inc;
    __syncthreads();
    if (threadIdx.x == 1023) carry_s = inc;
    __syncthreads();
  }
}

__global__ void csr_fill_kernel(const int* __restrict__ ei, const int* __restrict__ offs,
                                int* __restrict__ cnt2, int* __restrict__ csr_src) {
  int e = blockIdx.x * 256 + threadIdx.x;
  if (e < kE) {
    int d = ei[kE + e];
    int pos = offs[d] + atomicAdd(&cnt2[d], 1);
    csr_src[pos] = ei[e];
  }
}

// ---------------- GEMM 1: h[m] = x[m] @ Wg[m] ----------------

__global__ __launch_bounds__(256) void gemm_h_kernel(const float* __restrict__ X,
                                                     const float* __restrict__ Wg,
                                                     float* __restrict__ H) {
  const int m = blockIdx.z;
  const float* A = X + (size_t)m * kN * kD;
  const float* B = Wg + (size_t)m * kD * kD;
  float* C = H + (size_t)m * kN * kD;
  const int row0 = blockIdx.x * BM;
  const int col0 = blockIdx.y * BN;
  __shared__ __align__(16) float As[BK][BM + 4];  // stride 68 floats: 16B-aligned rows, 2-way banks
  __shared__ __align__(16) float Bs[BK][BN];
  const int tid = threadIdx.x;
  const int tm = tid >> 4, tn = tid & 15;
  float acc[4][4] = {};
  for (int k0 = 0; k0 < kD; k0 += BK) {
#pragma unroll
    for (int l = 0; l < 4; l++) {
      int e2 = tid + l * 256;
      int r = e2 >> 4, kk = e2 & 15;
      int gr = row0 + r;
      As[kk][r] = (gr < kN) ? A[(size_t)gr * kD + k0 + kk] : 0.f;
    }
#pragma unroll
    for (int l = 0; l < 4; l++) {
      int e2 = tid + l * 256;
      int kk = e2 >> 6, nn = e2 & 63;
      Bs[kk][nn] = B[(size_t)(k0 + kk) * kD + col0 + nn];
    }
    __syncthreads();
#pragma unroll
    for (int kk = 0; kk < BK; kk++) {
      float4 av = *(const float4*)&As[kk][tm * 4];
      float4 bv = *(const float4*)&Bs[kk][tn * 4];
      float a[4] = {av.x, av.y, av.z, av.w};
      float b[4] = {bv.x, bv.y, bv.z, bv.w};
#pragma unroll
      for (int i = 0; i < 4; i++)
#pragma unroll
        for (int j = 0; j < 4; j++) acc[i][j] += a[i] * b[j];
    }
    __syncthreads();
  }
#pragma unroll
  for (int i = 0; i < 4; i++) {
    int gr = row0 + tm * 4 + i;
    if (gr < kN) {
#pragma unroll
      for (int j = 0; j < 4; j++) C[(size_t)gr * kD + col0 + tn * 4 + j] = acc[i][j];
    }
  }
}

// ---------------- per-node attention logits ----------------

__global__ void dot_st_kernel(const float* __restrict__ H, const float* __restrict__ asrc,
                              const float* __restrict__ adst, float* __restrict__ sv,
                              float* __restrict__ tv) {
  int row = blockIdx.x * 4 + (threadIdx.x >> 6);  // flat m*N+n
  int lane = threadIdx.x & 63;
  if (row >= kM * kN) return;
  int m = row / kN;
  const float* hp = H + (size_t)row * kD;
  float s_ = 0.f, t_ = 0.f;
#pragma unroll
  for (int d0 = 0; d0 < kD; d0 += 64) {
    float hv = hp[d0 + lane];
    s_ += hv * asrc[m * kD + d0 + lane];
    t_ += hv * adst[m * kD + d0 + lane];
  }
#pragma unroll
  for (int o = 32; o > 0; o >>= 1) {
    s_ += __shfl_down(s_, o);
    t_ += __shfl_down(t_, o);
  }
  if (lane == 0) { sv[row] = s_; tv[row] = t_; }
}

// ---------------- fused weight/bias prep ----------------

__global__ void prep_kernel(const float* __restrict__ Wp, const float* __restrict__ bp,
                            const float* __restrict__ cw, const float* __restrict__ cb,
                            float* __restrict__ Wq, float* __restrict__ biasp) {
  int idx = blockIdx.x * 256 + threadIdx.x;
  if (idx < kM * kD * kP) Wq[idx] = cw[idx / (kD * kP)] * Wp[idx];
  if (idx < kP) {
    float v = cb[0];
#pragma unroll
    for (int m = 0; m < kM; m++) v += cw[m] * bp[m * kP + idx];
    biasp[idx] = v;
  }
}

// ---------------- GAT softmax + aggregate (per m,dst block) ----------------

__global__ __launch_bounds__(256) void gat_aggregate_kernel(
    const float* __restrict__ H, const float* __restrict__ sv, const float* __restrict__ tv,
    const float* __restrict__ bg, const int* __restrict__ offs, const int* __restrict__ csr_src,
    float* __restrict__ Hrel) {
  const int n = blockIdx.x;
  const int m = blockIdx.y;
  const int tid = threadIdx.x;
  __shared__ float e_buf[256];
  __shared__ int s_buf[256];
  __shared__ float red[256];

  const float tt = tv[m * kN + n];
  const int b = offs[n], eEnd = offs[n + 1];
  const int deg = eEnd - b;

  float a_self = sv[m * kN + n] + tt;
  a_self = a_self > 0.f ? a_self : kSlope * a_self;

  // pass 1: max over alphas (incl self)
  float lmax = a_self;
  for (int j = tid; j < deg; j += 256) {
    int src = csr_src[b + j];
    float a = sv[m * kN + src] + tt;
    a = a > 0.f ? a : kSlope * a;
    lmax = fmaxf(lmax, a);
  }
  red[tid] = lmax;
  __syncthreads();
  for (int o = 128; o > 0; o >>= 1) {
    if (tid < o) red[tid] = fmaxf(red[tid], red[tid + o]);
    __syncthreads();
  }
  const float mx = red[0];
  __syncthreads();

  const float e_self = __expf(a_self - mx);
  const int d = tid;  // feature dim
  float acc = e_self * H[((size_t)m * kN + n) * kD + d];
  float denom = e_self;

  for (int c0 = 0; c0 < deg; c0 += 256) {
    int j = c0 + tid;
    float ee = 0.f;
    if (j < deg) {
      int src = csr_src[b + j];
      s_buf[tid] = src;
      float a = sv[m * kN + src] + tt;
      a = a > 0.f ? a : kSlope * a;
      ee = __expf(a - mx);
      e_buf[tid] = ee;
    }
    red[tid] = ee;
    __syncthreads();
    for (int o = 128; o > 0; o >>= 1) {
      if (tid < o) red[tid] += red[tid + o];
      __syncthreads();
    }
    denom += red[0];
    int cl = min(256, deg - c0);
    for (int j2 = 0; j2 < cl; j2++) {
      acc += e_buf[j2] * H[((size_t)m * kN + s_buf[j2]) * kD + d];
    }
    __syncthreads();
  }

  float outv = acc / (denom + 1e-16f) + bg[m * kD + d];
  outv = outv > 0.f ? outv : 0.f;
  Hrel[((size_t)m * kN + n) * kD + d] = outv;
}

// ---------------- GEMM 2: fused = Hrel(view [N,1024]) @ Wq[1024,256] + biasp ----------------

__global__ __launch_bounds__(256) void gemm_fused_kernel(const float* __restrict__ Hrel,
                                                         const float* __restrict__ Wq,
                                                         const float* __restrict__ biasp,
                                                         float* __restrict__ Cout) {
  const int row0 = blockIdx.x * BM;
  const int col0 = blockIdx.y * BN;
  __shared__ __align__(16) float As[BK][BM + 4];
  __shared__ __align__(16) float Bs[BK][BN];
  const int tid = threadIdx.x;
  const int tm = tid >> 4, tn = tid & 15;
  float acc[4][4] = {};
  const int K = kM * kD;  // 1024
  for (int k0 = 0; k0 < K; k0 += BK) {
    const int mm = k0 >> 8;          // modality of this k-tile (BK=16 divides 256)
    const int dbase = k0 & 255;
    const float* A = Hrel + (size_t)mm * kN * kD;
#pragma unroll
    for (int l = 0; l < 4; l++) {
      int e2 = tid + l * 256;
      int r = e2 >> 4, kk = e2 & 15;
      int gr = row0 + r;
      As[kk][r] = (gr < kN) ? A[(size_t)gr * kD + dbase + kk] : 0.f;
    }
#pragma unroll
    for (int l = 0; l < 4; l++) {
      int e2 = tid + l * 256;
      int kk = e2 >> 6, nn = e2 & 63;
      Bs[kk][nn] = Wq[(size_t)(k0 + kk) * kP + col0 + nn];
    }
    __syncthreads();
#pragma unroll
    for (int kk = 0; kk < BK; kk++) {
      float4 av = *(const float4*)&As[kk][tm * 4];
      float4 bv = *(const float4*)&Bs[kk][tn * 4];
      float a[4] = {av.x, av.y, av.z, av.w};
      float b[4] = {bv.x, bv.y, bv.z, bv.w};
#pragma unroll
      for (int i = 0; i < 4; i++)
#pragma unroll
        for (int j = 0; j < 4; j++) acc[i][j] += a[i] * b[j];
    }
    __syncthreads();
  }
#pragma unroll
  for (int i = 0; i < 4; i++) {
    int gr = row0 + tm * 4 + i;
    if (gr < kN) {
#pragma unroll
      for (int j = 0; j < 4; j++)
        Cout[(size_t)gr * kP + col0 + tn * 4 + j] = acc[i][j] + biasp[col0 + tn * 4 + j];
    }
  }
}

// ---------------- host launch ----------------

extern "C" void kernel_launch(void* const* d_in, const int* in_sizes, int n_in,
                              void* d_out, int out_size, void* d_ws, size_t ws_size,
                              hipStream_t stream) {
  const float* x = (const float*)d_in[0];
  const int* ei = (const int*)d_in[1];
  const float* Wg = (const float*)d_in[2];
  const float* asrc = (const float*)d_in[3];
  const float* adst = (const float*)d_in[4];
  const float* bg = (const float*)d_in[5];
  const float* Wp = (const float*)d_in[6];
  const float* bp = (const float*)d_in[7];
  const float* cw = (const float*)d_in[8];
  const float* cb = (const float*)d_in[9];
  float* out = (float*)d_out;

  char* ws = (char*)d_ws;
  size_t off = 0;
  auto alloc = [&](size_t bytes) -> void* {
    void* p = ws + off;
    off = (off + bytes + 255) & ~(size_t)255;
    return p;
  };
  float* h = (float*)alloc((size_t)kM * kN * kD * sizeof(float));
  float* hrel = (float*)alloc((size_t)kM * kN * kD * sizeof(float));
  float* sv = (float*)alloc((size_t)kM * kN * sizeof(float));
  float* tv = (float*)alloc((size_t)kM * kN * sizeof(float));
  float* Wq = (float*)alloc((size_t)kM * kD * kP * sizeof(float));
  float* biasp = (float*)alloc(kP * sizeof(float));
  int* deg = (int*)alloc(kN * sizeof(int));
  int* cnt2 = (int*)alloc(kN * sizeof(int));
  int* offs = (int*)alloc((kN + 1) * sizeof(int));
  int* csr_src = (int*)alloc((size_t)kE * sizeof(int));

  hipMemsetAsync(deg, 0, kN * sizeof(int), stream);
  hipMemsetAsync(cnt2, 0, kN * sizeof(int), stream);

  deg_count_kernel<<<(kE + 255) / 256, 256, 0, stream>>>(ei, deg);
  scan_kernel<<<1, 1024, 0, stream>>>(deg, offs);
  csr_fill_kernel<<<(kE + 255) / 256, 256, 0, stream>>>(ei, offs, cnt2, csr_src);

  gemm_h_kernel<<<dim3((kN + BM - 1) / BM, kD / BN, kM), 256, 0, stream>>>(x, Wg, h);
  dot_st_kernel<<<(kM * kN) / 4, 256, 0, stream>>>(h, asrc, adst, sv, tv);
  prep_kernel<<<(kM * kD * kP + 255) / 256, 256, 0, stream>>>(Wp, bp, cw, cb, Wq, biasp);

  gat_aggregate_kernel<<<dim3(kN, kM), 256, 0, stream>>>(h, sv, tv, bg, offs, csr_src, hrel);

  gemm_fused_kernel<<<dim3((kN + BM - 1) / BM, kP / BN), 256, 0, stream>>>(hrel, Wq, biasp, out);
}